// Round 8
// baseline (210.096 us; speedup 1.0000x reference)
//
#include <hip/hip_runtime.h>
#include <hip/hip_cooperative_groups.h>

namespace cg = cooperative_groups;

#define Hh 384
#define Ww 384
#define Bb 4
#define NN 64
#define HW (Hh*Ww)
#define NSEG (NN-1)
#define GX 12                 // 12x12 tiles of 32x32 per batch
#define NTILES (GX*GX)        // 144 per batch
#define NPART (NTILES*Bb)     // 576 partials

// ---------------- compile-time Ainv = (I + 0.1*A)^-1 (banded LU, f32) ------
struct AinvT { float a[NN][NN]; };
constexpr AinvT make_ainv() {
    AinvT R{};
    float d[NN] = {}, u1[NN] = {}, u2[NN] = {}, b1[NN] = {}, L1[NN] = {}, L2[NN] = {};
    for (int k = 0; k < NN-1; ++k) { d[k] += 0.01f; d[k+1] += 0.01f; u1[k] -= 0.01f; }
    for (int k = 0; k < NN-2; ++k) {
        d[k] += 0.01f; d[k+1] += 0.04f; d[k+2] += 0.01f;
        u1[k] -= 0.02f; u1[k+1] -= 0.02f; u2[k] += 0.01f;
    }
    for (int k = 0; k < NN; ++k) {
        d[k]  = 1.0f + 0.1f*d[k];
        u1[k] = 0.1f*u1[k];
        u2[k] = 0.1f*u2[k];
        b1[k] = u1[k];
    }
    for (int k = 0; k < NN; ++k) {
        float di = d[k];
        if (k+1 < NN) { float l = b1[k]/di; L1[k] = l; d[k+1] -= l*u1[k]; if (k+2 < NN) u1[k+1] -= l*u2[k]; }
        if (k+2 < NN) { float l = u2[k]/di; L2[k] = l; b1[k+1] -= l*u1[k]; d[k+2] -= l*u2[k]; }
    }
    for (int t = 0; t < NN; ++t) {
        float y[NN] = {}, x[NN] = {};
        for (int k = 0; k < NN; ++k) {
            float v = (k == t) ? 1.0f : 0.0f;
            if (k >= 1) v -= L1[k-1]*y[k-1];
            if (k >= 2) v -= L2[k-2]*y[k-2];
            y[k] = v;
        }
        for (int kk = 0; kk < NN; ++kk) {
            int k = NN-1-kk;
            float v = y[k];
            if (k+1 < NN) v -= u1[k]*x[k+1];
            if (k+2 < NN) v -= u2[k]*x[k+2];
            x[k] = v/d[k];
        }
        for (int k = 0; k < NN; ++k) R.a[k][t] = x[k];
    }
    return R;
}
__device__ constexpr AinvT g_Ainv = make_ainv();

#define TILE 32
#define HALO 8

// ---------------- single cooperative mega-kernel ---------------------------
__global__ __launch_bounds__(256) void k_mega(const float* __restrict__ pred,
        const float* __restrict__ init, float2* __restrict__ gimg,
        float4* __restrict__ pA, float4* __restrict__ pB,
        float* __restrict__ partial, float* __restrict__ out) {
    cg::grid_group grid = cg::this_grid();

    __shared__ float sIn[TILE+2*HALO][TILE+2*HALO];      // 48x48 (conv)
    __shared__ float sColG[TILE+2*HALO][TILE];           // conv
    __shared__ float sColD[TILE+2*HALO][TILE];           // conv
    __shared__ float gtap[17], dtap[17];
    __shared__ float2 stxy[NN];                          // snake
    __shared__ float swf[NN];                            // snake widths
    __shared__ float4 sSa[NSEG], sSb[NSEG];              // render
    __shared__ int slist[NSEG];
    __shared__ int scount;
    __shared__ float red[256];
    __shared__ double dred[256];

    const int tid = threadIdx.x;
    const int bx = blockIdx.x, by = blockIdx.y, bz = blockIdx.z;

    // ================= phase 1: conv (each block one 32x32 tile) ===========
    {
        const int b  = bz;
        const int x0 = bx * TILE;
        const int y0 = by * TILE;
        if (tid == 0) {
            float s = 0.f;
            for (int i = 0; i < 17; ++i) {
                float xv = (float)(i - 8);
                float e  = expf(-0.5f * (xv*0.5f)*(xv*0.5f));
                gtap[i] = e; s += e;
                dtap[i] = -(xv*0.25f) * e;
            }
            for (int i = 0; i < 17; ++i) gtap[i] /= s;
        }
        const float* im = pred + (size_t)b*HW;
        for (int idx = tid; idx < 48*48; idx += 256) {
            int r = idx / 48, c = idx % 48;
            int gx = x0 + r - HALO, gy = y0 + c - HALO;
            float v = 0.f;
            if (gx >= 0 && gx < Hh && gy >= 0 && gy < Ww) v = im[gx*Ww + gy];
            sIn[r][c] = v;
        }
        __syncthreads();
        for (int idx = tid; idx < 48*TILE; idx += 256) {
            int r = idx / TILE, c = idx % TILE;
            float ag = 0.f, ad = 0.f;
#pragma unroll
            for (int k = 0; k < 17; ++k) {
                float v = sIn[r][c+k];
                ag += gtap[k]*v;
                ad += dtap[k]*v;
            }
            sColG[r][c] = ag; sColD[r][c] = ad;
        }
        __syncthreads();
        float2* gg = gimg + (size_t)b*HW;
        for (int idx = tid; idx < TILE*TILE; idx += 256) {
            int xo = idx / TILE, c = idx % TILE;
            float a0 = 0.f, a1 = 0.f;
#pragma unroll
            for (int k = 0; k < 17; ++k) {
                a0 += dtap[k]*sColG[xo+k][c];
                a1 += gtap[k]*sColD[xo+k][c];
            }
            int gx = x0+xo, gy = y0+c;
            gg[gx*Ww+gy] = make_float2(10.f*a0, 10.f*a1);
        }
    }
    grid.sync();

    // ===== phase 2: snake + widths + prep (blocks bx==0 && by==0 only) =====
    if (bx == 0 && by == 0) {
        const int b = bz;
        const int i = tid >> 2;
        const int q = tid & 3;

        float ar[16];
#pragma unroll
        for (int k = 0; k < 16; ++k) ar[k] = g_Ainv.a[i][q*16 + k];

        float px = init[(b*NN + i)*2 + 0];
        float py = init[(b*NN + i)*2 + 1];
        const float2* g = gimg + (size_t)b*HW;

        for (int s = 0; s < 20; ++s) {
            float x = fminf(fmaxf(px, 0.f), (float)(Hh-1));
            float y = fminf(fmaxf(py, 0.f), (float)(Ww-1));
            int x0i = (int)floorf(x); x0i = min(max(x0i, 0), Hh-2);
            int y0i = (int)floorf(y); y0i = min(max(y0i, 0), Ww-2);
            float fx = x - (float)x0i, fy = y - (float)y0i;
            int base = x0i*Ww + y0i;
            if (q == 0) {
                float2 v00 = g[base],    v01 = g[base+1];
                float2 v10 = g[base+Ww], v11 = g[base+Ww+1];
                float t0x = v00.x*(1.f-fy) + v01.x*fy;
                float t0y = v00.y*(1.f-fy) + v01.y*fy;
                float b0x = v10.x*(1.f-fy) + v11.x*fy;
                float b0y = v10.y*(1.f-fy) + v11.y*fy;
                float f0 = t0x*(1.f-fx) + b0x*fx;
                float f1 = t0y*(1.f-fx) + b0y*fx;
                stxy[i] = make_float2(px + 0.1f*f0, py + 0.1f*f1);
            }
            __syncthreads();
            float ax = 0.f, ay = 0.f;
#pragma unroll
            for (int k = 0; k < 16; ++k) {
                float2 tv = stxy[q*16 + k];
                ax = fmaf(ar[k], tv.x, ax);
                ay = fmaf(ar[k], tv.y, ay);
            }
            ax += __shfl_xor(ax, 1); ay += __shfl_xor(ay, 1);
            ax += __shfl_xor(ax, 2); ay += __shfl_xor(ay, 2);
            px = ax; py = ay;
            __syncthreads();
        }
        if (q == 0) stxy[i] = make_float2(px, py);
        __syncthreads();

        // lockstep radial widths: 4 waves x 16 node-rounds, ballot early exit
        const float* p = pred + (size_t)b*HW;
        const int wid  = tid >> 6;
        const int lane = tid & 63;
        const bool active = lane < 36;
        const float theta = (float)(10*lane) * 0.017453292519943295f;
        const float cth = cosf(theta), sth = sinf(theta);
        for (int nc = 0; nc < 16; ++nc) {
            const int node = wid*16 + nc;
            const float sx = rintf(stxy[node].x);
            const float sy = rintf(stxy[node].y);
            float w = 0.f;
            for (int r = 1; r < Hh; ++r) {
                float rf = (float)r;
                bool hit = false, oob = false;
                if (active) {
                    int xi = (int)floorf(sx + rf*cth);
                    int yi = (int)floorf(sy + rf*sth);
                    bool inb = (xi >= 0) & (xi < Hh) & (yi >= 0) & (yi < Ww);
                    if (!inb) oob = true;
                    else if (p[xi*Ww + yi] > 0.f) hit = true;  // sigmoid(-p)<0.5 <=> p>0
                }
                unsigned long long mh = __ballot(hit);
                unsigned long long mo = __ballot(oob);
                if (mh | mo) { w = mh ? (rf - 1.f) : 0.f; break; }
            }
            if (lane == 0) swf[node] = w;
        }
        __syncthreads();

        if (tid < NSEG) {
            float2 P0 = stxy[tid], P1 = stxy[tid+1];
            float vx = P1.x - P0.x, vy = P1.y - P0.y;
            float vv = vx*vx + vy*vy + 1e-8f;
            float w0 = swf[tid], w1 = swf[tid+1];
            pA[b*NSEG + tid] = make_float4(P0.x, P0.y, vx, vy);
            pB[b*NSEG + tid] = make_float4(1.0f/vv, w0, w1 - w0, 0.f);
        }
    }
    grid.sync();

    // ================= phase 3: render (32x32 tile, 4 px/thread) ===========
    {
        const int b = bz;
        const int row0 = bx * 32, col0 = by * 32;
        if (tid == 0) scount = 0;
        if (tid < NSEG) {
            sSa[tid] = pA[b*NSEG + tid];
            sSb[tid] = pB[b*NSEG + tid];
        }
        __syncthreads();
        if (tid < NSEG) {
            const float4 A = sSa[tid];
            const float4 Bv = sSb[tid];
            float cx = (float)row0 + 15.5f, cy = (float)col0 + 15.5f;
            float dx = cx - A.x, dy = cy - A.y;
            float t = fmaf(dy, A.w, dx*A.z) * Bv.x;
            t = fminf(fmaxf(t, 0.f), 1.f);
            float ex = fmaf(-t, A.z, dx);
            float ey = fmaf(-t, A.w, dy);
            float dc = sqrtf(ex*ex + ey*ey);
            float wmax = fmaxf(Bv.y, Bv.y + Bv.z);
            float lim = fmaxf(15.0f, wmax) + 21.93f + 0.05f;  // 32x32 tile radius + margin
            if (dc <= lim) {
                int idx = atomicAdd(&scount, 1);
                slist[idx] = tid;
            }
        }
        __syncthreads();
        const int cnt = scount;
        const int rr = tid >> 4, cc = tid & 15;
        const float fx0 = (float)(row0 + rr), fy0 = (float)(col0 + cc);
        float m1a = 1e30f, m2a = 1e30f, m1b = 1e30f, m2b = 1e30f;
        float m1c = 1e30f, m2c = 1e30f, m1d = 1e30f, m2d = 1e30f;
        for (int k = 0; k < cnt; ++k) {
            const int s2 = slist[k];
            const float4 A = sSa[s2];
            const float4 Bv = sSb[s2];
#define SEGPX(FX, FY, M1, M2) { \
            float dx = (FX) - A.x, dy = (FY) - A.y; \
            float t = fmaf(dy, A.w, dx*A.z) * Bv.x; \
            t = fminf(fmaxf(t, 0.f), 1.f); \
            float ex = fmaf(-t, A.z, dx); \
            float ey = fmaf(-t, A.w, dy); \
            float d2 = fmaf(ex, ex, fmaf(ey, ey, 1e-12f)); \
            float wt = fmaf(t, Bv.z, Bv.y); \
            M1 = fminf(M1, d2); \
            M2 = fminf(M2, fmaf(-wt, wt, d2)); }
            SEGPX(fx0,       fy0,       m1a, m2a);
            SEGPX(fx0,       fy0+16.f,  m1b, m2b);
            SEGPX(fx0+16.f,  fy0,       m1c, m2c);
            SEGPX(fx0+16.f,  fy0+16.f,  m1d, m2d);
#undef SEGPX
        }
        const float* pp = pred + (size_t)b*HW;
        float accv = 0.f;
#define TAILPX(M1, M2, R, C) { \
        float dmap = fminf(sqrtf(M1), 15.f); \
        float pm = ((M2) <= 0.f) ? 1.f : 0.f; \
        float pv = pp[(R)*Ww + (C)]; \
        float sg = 1.f/(1.f + expf(-pv)); \
        float t1 = pv - dmap, t2 = sg - pm; \
        accv += t1*t1 + t2*t2; }
        TAILPX(m1a, m2a, row0 + rr,      col0 + cc);
        TAILPX(m1b, m2b, row0 + rr,      col0 + cc + 16);
        TAILPX(m1c, m2c, row0 + rr + 16, col0 + cc);
        TAILPX(m1d, m2d, row0 + rr + 16, col0 + cc + 16);
#undef TAILPX
        red[tid] = accv;
        __syncthreads();
        for (int off = 128; off > 0; off >>= 1) {
            if (tid < off) red[tid] += red[tid+off];
            __syncthreads();
        }
        if (tid == 0)
            partial[b*NTILES + by*GX + bx] = red[0];
    }
    grid.sync();

    // ================= phase 4: final reduction (block 0 only) =============
    if (bx == 0 && by == 0 && bz == 0) {
        double a = 0.0;
        for (int i2 = tid; i2 < NPART; i2 += 256) a += (double)partial[i2];
        dred[tid] = a; __syncthreads();
        for (int off = 128; off > 0; off >>= 1) {
            if (tid < off) dred[tid] += dred[tid+off];
            __syncthreads();
        }
        if (tid == 0) out[0] = (float)(dred[0] / (double)((size_t)Bb*HW));
    }
}

extern "C" void kernel_launch(void* const* d_in, const int* in_sizes, int n_in,
                              void* d_out, int out_size, void* d_ws, size_t ws_size,
                              hipStream_t stream) {
    const float* pred = (const float*)d_in[0];   // [4,1,384,384] f32
    const float* init = (const float*)d_in[1];   // [4,64,2] f32
    float* out = (float*)d_out;
    char* ws = (char*)d_ws;
    // ws: pA @0 | pB @4096 | partial @19456 (576 f32) | gimg @28672
    float4* pA     = (float4*)(ws);
    float4* pB     = (float4*)(ws + 4096);
    float* partial = (float*)(ws + 19456);
    float2* gimg   = (float2*)(ws + 28672);

    void* args[] = { (void*)&pred, (void*)&init, (void*)&gimg,
                     (void*)&pA, (void*)&pB, (void*)&partial, (void*)&out };
    hipLaunchCooperativeKernel((const void*)k_mega, dim3(GX,GX,Bb), dim3(256),
                               args, 0, stream);
}

// Round 9
// 82.370 us; speedup vs baseline: 2.5506x; 2.5506x over previous
//
#include <hip/hip_runtime.h>

#define Hh 384
#define Ww 384
#define Bb 4
#define NN 64
#define HW (Hh*Ww)
#define NSEG (NN-1)
#define TPB 24                        // 24x24 tiles of 16x16
#define NTILES (TPB*TPB)              // 576 per batch
#define NPART (NTILES*Bb)             // 2304 partials

// ---------------- compile-time Ainv = (I + 0.1*A)^-1 (banded LU, f32) ------
struct AinvT { float a[NN][NN]; };
constexpr AinvT make_ainv() {
    AinvT R{};
    float d[NN] = {}, u1[NN] = {}, u2[NN] = {}, b1[NN] = {}, L1[NN] = {}, L2[NN] = {};
    for (int k = 0; k < NN-1; ++k) { d[k] += 0.01f; d[k+1] += 0.01f; u1[k] -= 0.01f; }
    for (int k = 0; k < NN-2; ++k) {
        d[k] += 0.01f; d[k+1] += 0.04f; d[k+2] += 0.01f;
        u1[k] -= 0.02f; u1[k+1] -= 0.02f; u2[k] += 0.01f;
    }
    for (int k = 0; k < NN; ++k) {
        d[k]  = 1.0f + 0.1f*d[k];
        u1[k] = 0.1f*u1[k];
        u2[k] = 0.1f*u2[k];
        b1[k] = u1[k];
    }
    for (int k = 0; k < NN; ++k) {
        float di = d[k];
        if (k+1 < NN) { float l = b1[k]/di; L1[k] = l; d[k+1] -= l*u1[k]; if (k+2 < NN) u1[k+1] -= l*u2[k]; }
        if (k+2 < NN) { float l = u2[k]/di; L2[k] = l; b1[k+1] -= l*u1[k]; d[k+2] -= l*u2[k]; }
    }
    for (int t = 0; t < NN; ++t) {
        float y[NN] = {}, x[NN] = {};
        for (int k = 0; k < NN; ++k) {
            float v = (k == t) ? 1.0f : 0.0f;
            if (k >= 1) v -= L1[k-1]*y[k-1];
            if (k >= 2) v -= L2[k-2]*y[k-2];
            y[k] = v;
        }
        for (int kk = 0; kk < NN; ++kk) {
            int k = NN-1-kk;
            float v = y[k];
            if (k+1 < NN) v -= u1[k]*x[k+1];
            if (k+2 < NN) v -= u2[k]*x[k+2];
            x[k] = v/d[k];
        }
        for (int k = 0; k < NN; ++k) R.a[k][t] = x[k];
    }
    return R;
}
__device__ constexpr AinvT g_Ainv = make_ainv();

// ---------------- conv (separable DoG) -> gimg [B][H][W][2] ----------------
#define TILE 32
#define HALO 8
__global__ __launch_bounds__(256) void k_conv(const float* __restrict__ img,
        float2* __restrict__ gimg) {
    __shared__ float sIn[TILE+2*HALO][TILE+2*HALO];      // 48x48
    __shared__ float sColG[TILE+2*HALO][TILE];
    __shared__ float sColD[TILE+2*HALO][TILE];
    __shared__ float gtap[17], dtap[17];
    const int b  = blockIdx.z;
    const int x0 = blockIdx.x * TILE;
    const int y0 = blockIdx.y * TILE;
    const int tid = threadIdx.x;
    if (tid == 0) {
        float s = 0.f;
        for (int i = 0; i < 17; ++i) {
            float xv = (float)(i - 8);
            float e  = expf(-0.5f * (xv*0.5f)*(xv*0.5f));
            gtap[i] = e; s += e;
            dtap[i] = -(xv*0.25f) * e;
        }
        for (int i = 0; i < 17; ++i) gtap[i] /= s;
    }
    const float* im = img + b*HW;
    for (int idx = tid; idx < 48*48; idx += blockDim.x) {
        int r = idx / 48, c = idx % 48;
        int gx = x0 + r - HALO, gy = y0 + c - HALO;
        float v = 0.f;
        if (gx >= 0 && gx < Hh && gy >= 0 && gy < Ww) v = im[gx*Ww + gy];
        sIn[r][c] = v;
    }
    __syncthreads();
    for (int idx = tid; idx < 48*TILE; idx += blockDim.x) {
        int r = idx / TILE, c = idx % TILE;
        float ag = 0.f, ad = 0.f;
#pragma unroll
        for (int k = 0; k < 17; ++k) {
            float v = sIn[r][c+k];
            ag += gtap[k]*v;
            ad += dtap[k]*v;
        }
        sColG[r][c] = ag; sColD[r][c] = ad;
    }
    __syncthreads();
    float2* gg = gimg + (size_t)b*HW;
    for (int idx = tid; idx < TILE*TILE; idx += blockDim.x) {
        int xo = idx / TILE, c = idx % TILE;
        float a0 = 0.f, a1 = 0.f;
#pragma unroll
        for (int k = 0; k < 17; ++k) {
            a0 += dtap[k]*sColG[xo+k][c];
            a1 += gtap[k]*sColD[xo+k][c];
        }
        int gx = x0+xo, gy = y0+c;
        gg[gx*Ww+gy] = make_float2(10.f*a0, 10.f*a1);
    }
}

// ------- snake (20 steps, const Ainv) + lockstep widths + segment prep -----
__global__ __launch_bounds__(256) void k_snake(const float2* __restrict__ gimg,
                        const float* __restrict__ pred, const float* __restrict__ init,
                        float4* __restrict__ pA, float4* __restrict__ pB,
                        unsigned int* __restrict__ count) {
    __shared__ float2 stxy[NN];
    __shared__ float swf[NN];
    const int b = blockIdx.x;
    const int tid = threadIdx.x;
    const int i = tid >> 2;
    const int q = tid & 3;

    if (b == 0 && tid == 0) *count = 0u;   // reset render ticket every call

    float ar[16];
#pragma unroll
    for (int k = 0; k < 16; ++k) ar[k] = g_Ainv.a[i][q*16 + k];

    float px = init[(b*NN + i)*2 + 0];
    float py = init[(b*NN + i)*2 + 1];
    const float2* g = gimg + (size_t)b*HW;

    for (int s = 0; s < 20; ++s) {
        float x = fminf(fmaxf(px, 0.f), (float)(Hh-1));
        float y = fminf(fmaxf(py, 0.f), (float)(Ww-1));
        int x0i = (int)floorf(x); x0i = min(max(x0i, 0), Hh-2);
        int y0i = (int)floorf(y); y0i = min(max(y0i, 0), Ww-2);
        float fx = x - (float)x0i, fy = y - (float)y0i;
        int base = x0i*Ww + y0i;
        if (q == 0) {
            float2 v00 = g[base],    v01 = g[base+1];
            float2 v10 = g[base+Ww], v11 = g[base+Ww+1];
            float t0x = v00.x*(1.f-fy) + v01.x*fy;
            float t0y = v00.y*(1.f-fy) + v01.y*fy;
            float b0x = v10.x*(1.f-fy) + v11.x*fy;
            float b0y = v10.y*(1.f-fy) + v11.y*fy;
            float f0 = t0x*(1.f-fx) + b0x*fx;
            float f1 = t0y*(1.f-fx) + b0y*fx;
            stxy[i] = make_float2(px + 0.1f*f0, py + 0.1f*f1);
        }
        __syncthreads();
        float ax = 0.f, ay = 0.f;
#pragma unroll
        for (int k = 0; k < 16; ++k) {
            float2 tv = stxy[q*16 + k];
            ax = fmaf(ar[k], tv.x, ax);
            ay = fmaf(ar[k], tv.y, ay);
        }
        ax += __shfl_xor(ax, 1); ay += __shfl_xor(ay, 1);
        ax += __shfl_xor(ax, 2); ay += __shfl_xor(ay, 2);
        px = ax; py = ay;
        __syncthreads();
    }
    if (q == 0) stxy[i] = make_float2(px, py);
    __syncthreads();

    // ---- lockstep radial widths: 4 waves x 16 node-rounds, ballot exit ----
    const float* p = pred + (size_t)b*HW;
    const int wid  = tid >> 6;
    const int lane = tid & 63;
    const bool active = lane < 36;
    const float theta = (float)(10*lane) * 0.017453292519943295f;
    const float cth = cosf(theta), sth = sinf(theta);
    for (int nc = 0; nc < 16; ++nc) {
        const int node = wid*16 + nc;
        const float sx = rintf(stxy[node].x);
        const float sy = rintf(stxy[node].y);
        float w = 0.f;
        for (int r = 1; r < Hh; ++r) {
            float rf = (float)r;
            bool hit = false, oob = false;
            if (active) {
                int xi = (int)floorf(sx + rf*cth);
                int yi = (int)floorf(sy + rf*sth);
                bool inb = (xi >= 0) & (xi < Hh) & (yi >= 0) & (yi < Ww);
                if (!inb) oob = true;
                else if (p[xi*Ww + yi] > 0.f) hit = true;   // sigmoid(-p)<0.5 <=> p>0
            }
            unsigned long long mh = __ballot(hit);
            unsigned long long mo = __ballot(oob);
            if (mh | mo) { w = mh ? (rf - 1.f) : 0.f; break; }
        }
        if (lane == 0) swf[node] = w;
    }
    __syncthreads();

    // ---- segment prep ----
    if (tid < NSEG) {
        float2 P0 = stxy[tid], P1 = stxy[tid+1];
        float vx = P1.x - P0.x, vy = P1.y - P0.y;
        float vv = vx*vx + vy*vy + 1e-8f;
        float w0 = swf[tid], w1 = swf[tid+1];
        pA[b*NSEG + tid] = make_float4(P0.x, P0.y, vx, vy);
        pB[b*NSEG + tid] = make_float4(1.0f/vv, w0, w1 - w0, 0.f);
    }
}

// ------- render: 16x16 tiles, cull, partial sums; last block reduces -------
__global__ __launch_bounds__(256) void k_render(const float* __restrict__ pred,
                        const float4* __restrict__ pAg, const float4* __restrict__ pBg,
                        float* __restrict__ partial, unsigned int* __restrict__ count,
                        float* __restrict__ out) {
    __shared__ float4 sSa[NSEG], sSb[NSEG];
    __shared__ int slist[NSEG];
    __shared__ int scount;
    __shared__ float red[256];
    __shared__ int slast;
    const int b   = blockIdx.z;
    const int tid = threadIdx.x;
    const int row0 = blockIdx.x * 16, col0 = blockIdx.y * 16;
    if (tid == 0) scount = 0;
    if (tid < NSEG) {
        sSa[tid] = pAg[b*NSEG + tid];
        sSb[tid] = pBg[b*NSEG + tid];
    }
    __syncthreads();
    if (tid < NSEG) {
        const float4 A = sSa[tid];
        const float4 Bv = sSb[tid];
        float cx = (float)row0 + 7.5f, cy = (float)col0 + 7.5f;
        float dx = cx - A.x, dy = cy - A.y;
        float t = fmaf(dy, A.w, dx*A.z) * Bv.x;
        t = fminf(fmaxf(t, 0.f), 1.f);
        float ex = fmaf(-t, A.z, dx);
        float ey = fmaf(-t, A.w, dy);
        float dc = sqrtf(ex*ex + ey*ey);
        float wmax = fmaxf(Bv.y, Bv.y + Bv.z);
        float lim = fmaxf(15.0f, wmax) + 10.6066f + 0.05f;
        if (dc <= lim) {
            int idx = atomicAdd(&scount, 1);
            slist[idx] = tid;
        }
    }
    __syncthreads();
    const int cnt = scount;
    const int r = tid >> 4, c = tid & 15;
    const float fx = (float)(row0 + r), fy = (float)(col0 + c);
    float m1 = 1e30f, m2 = 1e30f;
    for (int k = 0; k < cnt; ++k) {
        const int s2 = slist[k];
        const float4 A = sSa[s2];
        const float4 Bv = sSb[s2];
        float dx = fx - A.x, dy = fy - A.y;
        float t = fmaf(dy, A.w, dx*A.z) * Bv.x;
        t = fminf(fmaxf(t, 0.f), 1.f);
        float ex = fmaf(-t, A.z, dx);
        float ey = fmaf(-t, A.w, dy);
        float d2 = fmaf(ex, ex, fmaf(ey, ey, 1e-12f));
        float wt = fmaf(t, Bv.z, Bv.y);
        m1 = fminf(m1, d2);
        m2 = fminf(m2, fmaf(-wt, wt, d2));
    }
    float dmap = fminf(sqrtf(m1), 15.f);
    float pm = (m2 <= 0.f) ? 1.f : 0.f;
    float pv = pred[(size_t)b*HW + (row0 + r)*Ww + (col0 + c)];
    float sg = 1.f/(1.f + expf(-pv));
    float t1 = pv - dmap, t2 = sg - pm;
    red[tid] = t1*t1 + t2*t2;
    __syncthreads();
    for (int off = 128; off > 0; off >>= 1) {
        if (tid < off) red[tid] += red[tid+off];
        __syncthreads();
    }
    if (tid == 0) {
        partial[b*NTILES + blockIdx.y*TPB + blockIdx.x] = red[0];
        __threadfence();
        unsigned int done = atomicAdd(count, 1u);
        slast = (done == NPART - 1) ? 1 : 0;
    }
    __syncthreads();
    if (slast) {
        __threadfence();                 // acquire: others' partials visible
        __shared__ double dred[256];
        double a = 0.0;
        for (int i2 = tid; i2 < NPART; i2 += 256) a += (double)partial[i2];
        dred[tid] = a; __syncthreads();
        for (int off = 128; off > 0; off >>= 1) {
            if (tid < off) dred[tid] += dred[tid+off];
            __syncthreads();
        }
        if (tid == 0) out[0] = (float)(dred[0] / (double)((size_t)Bb*HW));
    }
}

extern "C" void kernel_launch(void* const* d_in, const int* in_sizes, int n_in,
                              void* d_out, int out_size, void* d_ws, size_t ws_size,
                              hipStream_t stream) {
    const float* pred = (const float*)d_in[0];   // [4,1,384,384] f32
    const float* init = (const float*)d_in[1];   // [4,64,2] f32
    float* out = (float*)d_out;
    char* ws = (char*)d_ws;
    // ws: pA @0 | pB @4096 | count @16384 | partial @19456 (2304 f32) | gimg @28672
    float4* pA     = (float4*)(ws);
    float4* pB     = (float4*)(ws + 4096);
    unsigned int* count = (unsigned int*)(ws + 16384);
    float* partial = (float*)(ws + 19456);
    float2* gimg   = (float2*)(ws + 28672);

    k_conv  <<<dim3(12,12,4),     dim3(256), 0, stream>>>(pred, gimg);
    k_snake <<<dim3(4),           dim3(256), 0, stream>>>(gimg, pred, init, pA, pB, count);
    k_render<<<dim3(TPB,TPB,Bb),  dim3(256), 0, stream>>>(pred, pA, pB, partial, count, out);
}

// Round 10
// 45.050 us; speedup vs baseline: 4.6636x; 1.8284x over previous
//
#include <hip/hip_runtime.h>

#define Hh 384
#define Ww 384
#define Bb 4
#define NN 64
#define HW (Hh*Ww)
#define NSEG (NN-1)
#define TPB 24                        // 24x24 tiles of 16x16
#define NTILES (TPB*TPB)              // 576 per batch

// ---------------- compile-time Ainv = (I + 0.1*A)^-1 (banded LU, f32) ------
struct AinvT { float a[NN][NN]; };
constexpr AinvT make_ainv() {
    AinvT R{};
    float d[NN] = {}, u1[NN] = {}, u2[NN] = {}, b1[NN] = {}, L1[NN] = {}, L2[NN] = {};
    for (int k = 0; k < NN-1; ++k) { d[k] += 0.01f; d[k+1] += 0.01f; u1[k] -= 0.01f; }
    for (int k = 0; k < NN-2; ++k) {
        d[k] += 0.01f; d[k+1] += 0.04f; d[k+2] += 0.01f;
        u1[k] -= 0.02f; u1[k+1] -= 0.02f; u2[k] += 0.01f;
    }
    for (int k = 0; k < NN; ++k) {
        d[k]  = 1.0f + 0.1f*d[k];
        u1[k] = 0.1f*u1[k];
        u2[k] = 0.1f*u2[k];
        b1[k] = u1[k];
    }
    for (int k = 0; k < NN; ++k) {
        float di = d[k];
        if (k+1 < NN) { float l = b1[k]/di; L1[k] = l; d[k+1] -= l*u1[k]; if (k+2 < NN) u1[k+1] -= l*u2[k]; }
        if (k+2 < NN) { float l = u2[k]/di; L2[k] = l; b1[k+1] -= l*u1[k]; d[k+2] -= l*u2[k]; }
    }
    for (int t = 0; t < NN; ++t) {
        float y[NN] = {}, x[NN] = {};
        for (int k = 0; k < NN; ++k) {
            float v = (k == t) ? 1.0f : 0.0f;
            if (k >= 1) v -= L1[k-1]*y[k-1];
            if (k >= 2) v -= L2[k-2]*y[k-2];
            y[k] = v;
        }
        for (int kk = 0; kk < NN; ++kk) {
            int k = NN-1-kk;
            float v = y[k];
            if (k+1 < NN) v -= u1[k]*x[k+1];
            if (k+2 < NN) v -= u2[k]*x[k+2];
            x[k] = v/d[k];
        }
        for (int k = 0; k < NN; ++k) R.a[k][t] = x[k];
    }
    return R;
}
__device__ constexpr AinvT g_Ainv = make_ainv();

// ---------------- conv (separable DoG) -> gimg [B][H][W][2] ----------------
#define TILE 32
#define HALO 8
__global__ __launch_bounds__(256) void k_conv(const float* __restrict__ img,
        float2* __restrict__ gimg) {
    __shared__ float sIn[TILE+2*HALO][TILE+2*HALO];      // 48x48
    __shared__ float sColG[TILE+2*HALO][TILE];
    __shared__ float sColD[TILE+2*HALO][TILE];
    __shared__ float gtap[17], dtap[17];
    const int b  = blockIdx.z;
    const int x0 = blockIdx.x * TILE;
    const int y0 = blockIdx.y * TILE;
    const int tid = threadIdx.x;
    if (tid == 0) {
        float s = 0.f;
        for (int i = 0; i < 17; ++i) {
            float xv = (float)(i - 8);
            float e  = expf(-0.5f * (xv*0.5f)*(xv*0.5f));
            gtap[i] = e; s += e;
            dtap[i] = -(xv*0.25f) * e;
        }
        for (int i = 0; i < 17; ++i) gtap[i] /= s;
    }
    const float* im = img + b*HW;
    for (int idx = tid; idx < 48*48; idx += blockDim.x) {
        int r = idx / 48, c = idx % 48;
        int gx = x0 + r - HALO, gy = y0 + c - HALO;
        float v = 0.f;
        if (gx >= 0 && gx < Hh && gy >= 0 && gy < Ww) v = im[gx*Ww + gy];
        sIn[r][c] = v;
    }
    __syncthreads();
    for (int idx = tid; idx < 48*TILE; idx += blockDim.x) {
        int r = idx / TILE, c = idx % TILE;
        float ag = 0.f, ad = 0.f;
#pragma unroll
        for (int k = 0; k < 17; ++k) {
            float v = sIn[r][c+k];
            ag += gtap[k]*v;
            ad += dtap[k]*v;
        }
        sColG[r][c] = ag; sColD[r][c] = ad;
    }
    __syncthreads();
    float2* gg = gimg + (size_t)b*HW;
    for (int idx = tid; idx < TILE*TILE; idx += blockDim.x) {
        int xo = idx / TILE, c = idx % TILE;
        float a0 = 0.f, a1 = 0.f;
#pragma unroll
        for (int k = 0; k < 17; ++k) {
            a0 += dtap[k]*sColG[xo+k][c];
            a1 += gtap[k]*sColD[xo+k][c];
        }
        int gx = x0+xo, gy = y0+c;
        gg[gx*Ww+gy] = make_float2(10.f*a0, 10.f*a1);
    }
}

// ------- snake (20 steps, const Ainv) + pipelined widths + segment prep ----
__global__ __launch_bounds__(256) void k_snake(const float2* __restrict__ gimg,
                        const float* __restrict__ pred, const float* __restrict__ init,
                        float4* __restrict__ pA, float4* __restrict__ pB) {
    __shared__ float2 stxy[NN];
    __shared__ float swf[NN];
    const int b = blockIdx.x;
    const int tid = threadIdx.x;
    const int i = tid >> 2;
    const int q = tid & 3;

    float ar[16];
#pragma unroll
    for (int k = 0; k < 16; ++k) ar[k] = g_Ainv.a[i][q*16 + k];

    float px = init[(b*NN + i)*2 + 0];
    float py = init[(b*NN + i)*2 + 1];
    const float2* g = gimg + (size_t)b*HW;

    for (int s = 0; s < 20; ++s) {
        float x = fminf(fmaxf(px, 0.f), (float)(Hh-1));
        float y = fminf(fmaxf(py, 0.f), (float)(Ww-1));
        int x0i = (int)floorf(x); x0i = min(max(x0i, 0), Hh-2);
        int y0i = (int)floorf(y); y0i = min(max(y0i, 0), Ww-2);
        float fx = x - (float)x0i, fy = y - (float)y0i;
        int base = x0i*Ww + y0i;
        if (q == 0) {
            float2 v00 = g[base],    v01 = g[base+1];
            float2 v10 = g[base+Ww], v11 = g[base+Ww+1];
            float t0x = v00.x*(1.f-fy) + v01.x*fy;
            float t0y = v00.y*(1.f-fy) + v01.y*fy;
            float b0x = v10.x*(1.f-fy) + v11.x*fy;
            float b0y = v10.y*(1.f-fy) + v11.y*fy;
            float f0 = t0x*(1.f-fx) + b0x*fx;
            float f1 = t0y*(1.f-fx) + b0y*fx;
            stxy[i] = make_float2(px + 0.1f*f0, py + 0.1f*f1);
        }
        __syncthreads();
        float ax = 0.f, ay = 0.f;
#pragma unroll
        for (int k = 0; k < 16; ++k) {
            float2 tv = stxy[q*16 + k];
            ax = fmaf(ar[k], tv.x, ax);
            ay = fmaf(ar[k], tv.y, ay);
        }
        ax += __shfl_xor(ax, 1); ay += __shfl_xor(ay, 1);
        ax += __shfl_xor(ax, 2); ay += __shfl_xor(ay, 2);
        px = ax; py = ay;
        __syncthreads();
    }
    if (q == 0) stxy[i] = make_float2(px, py);
    __syncthreads();

    // ---- lockstep radial widths: 4 waves x 16 node-rounds ----
    // Speculative 8-radius batches, software-pipelined across nodes:
    // node nc+1's loads are issued before node nc's ballots (all positions
    // known upfront). Per-radius ballot order identical to reference.
    const float* p = pred + (size_t)b*HW;
    const int wid  = tid >> 6;
    const int lane = tid & 63;
    const bool active = lane < 36;
    const float theta = (float)(10*lane) * 0.017453292519943295f;
    const float cth = cosf(theta), sth = sinf(theta);

    float valA[8], valB[8];
    unsigned inbA = 0u, inbB = 0u;

#define ISSUE(NC, VAL, INB) { \
    const int node_ = wid*16 + (NC); \
    const float sx_ = rintf(stxy[node_].x); \
    const float sy_ = rintf(stxy[node_].y); \
    unsigned m_ = 0u; \
    _Pragma("unroll") \
    for (int j = 0; j < 8; ++j) { \
        float rf_ = (float)(j+1); \
        int xi_ = (int)floorf(sx_ + rf_*cth); \
        int yi_ = (int)floorf(sy_ + rf_*sth); \
        bool inb_ = (xi_ >= 0) & (xi_ < Hh) & (yi_ >= 0) & (yi_ < Ww); \
        m_ |= (inb_ ? 1u : 0u) << j; \
        int cx_ = min(max(xi_, 0), Hh-1); \
        int cy_ = min(max(yi_, 0), Ww-1); \
        VAL[j] = p[cx_*Ww + cy_]; \
    } \
    INB = active ? m_ : 0u; }

#define PROCESS(NC, VAL, INB) { \
    const int node_ = wid*16 + (NC); \
    float w_ = 0.f; bool done_ = false; \
    _Pragma("unroll") \
    for (int j = 0; j < 8; ++j) { \
        if (!done_) { \
            bool inb_ = ((INB) >> j) & 1u; \
            bool hit_ = inb_ && (VAL[j] > 0.f); \
            bool oob_ = active && !inb_; \
            unsigned long long mh_ = __ballot(hit_); \
            unsigned long long mo_ = __ballot(oob_); \
            if (mh_ | mo_) { w_ = mh_ ? (float)j : 0.f; done_ = true; } \
        } \
    } \
    if (!done_) { \
        const float sx_ = rintf(stxy[node_].x); \
        const float sy_ = rintf(stxy[node_].y); \
        for (int r = 9; r < Hh; ++r) { \
            float rf_ = (float)r; \
            bool hit_ = false, oob_ = false; \
            if (active) { \
                int xi_ = (int)floorf(sx_ + rf_*cth); \
                int yi_ = (int)floorf(sy_ + rf_*sth); \
                bool inb_ = (xi_ >= 0) & (xi_ < Hh) & (yi_ >= 0) & (yi_ < Ww); \
                if (!inb_) oob_ = true; \
                else if (p[xi_*Ww + yi_] > 0.f) hit_ = true; \
            } \
            unsigned long long mh_ = __ballot(hit_); \
            unsigned long long mo_ = __ballot(oob_); \
            if (mh_ | mo_) { w_ = mh_ ? (rf_ - 1.f) : 0.f; break; } \
        } \
    } \
    if (lane == 0) swf[node_] = w_; }

    ISSUE(0, valA, inbA);
    for (int nc = 0; nc < 16; ++nc) {
        if (nc < 15) ISSUE(nc+1, valB, inbB);
        PROCESS(nc, valA, inbA);
#pragma unroll
        for (int j = 0; j < 8; ++j) valA[j] = valB[j];
        inbA = inbB;
    }
#undef ISSUE
#undef PROCESS
    __syncthreads();

    // ---- segment prep ----
    if (tid < NSEG) {
        float2 P0 = stxy[tid], P1 = stxy[tid+1];
        float vx = P1.x - P0.x, vy = P1.y - P0.y;
        float vv = vx*vx + vy*vy + 1e-8f;
        float w0 = swf[tid], w1 = swf[tid+1];
        pA[b*NSEG + tid] = make_float4(P0.x, P0.y, vx, vy);
        pB[b*NSEG + tid] = make_float4(1.0f/vv, w0, w1 - w0, 0.f);
    }
}

// ------- render: 16x16 tiles, LDS-staged params, per-tile segment culling --
__global__ __launch_bounds__(256) void k_render(const float* __restrict__ pred,
                        const float4* __restrict__ pAg, const float4* __restrict__ pBg,
                        float* __restrict__ partial) {
    __shared__ float4 sSa[NSEG], sSb[NSEG];
    __shared__ int slist[NSEG];
    __shared__ int scount;
    __shared__ float red[256];
    const int b   = blockIdx.z;
    const int tid = threadIdx.x;
    const int row0 = blockIdx.x * 16, col0 = blockIdx.y * 16;
    if (tid == 0) scount = 0;
    if (tid < NSEG) {
        sSa[tid] = pAg[b*NSEG + tid];
        sSb[tid] = pBg[b*NSEG + tid];
    }
    __syncthreads();
    if (tid < NSEG) {
        const float4 A = sSa[tid];
        const float4 Bv = sSb[tid];
        float cx = (float)row0 + 7.5f, cy = (float)col0 + 7.5f;
        float dx = cx - A.x, dy = cy - A.y;
        float t = fmaf(dy, A.w, dx*A.z) * Bv.x;
        t = fminf(fmaxf(t, 0.f), 1.f);
        float ex = fmaf(-t, A.z, dx);
        float ey = fmaf(-t, A.w, dy);
        float dc = sqrtf(ex*ex + ey*ey);
        float wmax = fmaxf(Bv.y, Bv.y + Bv.z);
        float lim = fmaxf(15.0f, wmax) + 10.6066f + 0.05f;
        if (dc <= lim) {
            int idx = atomicAdd(&scount, 1);
            slist[idx] = tid;
        }
    }
    __syncthreads();
    const int cnt = scount;
    const int r = tid >> 4, c = tid & 15;
    const float fx = (float)(row0 + r), fy = (float)(col0 + c);
    float m1 = 1e30f, m2 = 1e30f;
    for (int k = 0; k < cnt; ++k) {
        const int s2 = slist[k];
        const float4 A = sSa[s2];
        const float4 Bv = sSb[s2];
        float dx = fx - A.x, dy = fy - A.y;
        float t = fmaf(dy, A.w, dx*A.z) * Bv.x;
        t = fminf(fmaxf(t, 0.f), 1.f);
        float ex = fmaf(-t, A.z, dx);
        float ey = fmaf(-t, A.w, dy);
        float d2 = fmaf(ex, ex, fmaf(ey, ey, 1e-12f));
        float wt = fmaf(t, Bv.z, Bv.y);
        m1 = fminf(m1, d2);
        m2 = fminf(m2, fmaf(-wt, wt, d2));
    }
    float dmap = fminf(sqrtf(m1), 15.f);
    float pm = (m2 <= 0.f) ? 1.f : 0.f;
    float pv = pred[(size_t)b*HW + (row0 + r)*Ww + (col0 + c)];
    float sg = 1.f/(1.f + expf(-pv));
    float t1 = pv - dmap, t2 = sg - pm;
    red[tid] = t1*t1 + t2*t2;
    __syncthreads();
    for (int off = 128; off > 0; off >>= 1) {
        if (tid < off) red[tid] += red[tid+off];
        __syncthreads();
    }
    if (tid == 0)
        partial[b*NTILES + blockIdx.y*TPB + blockIdx.x] = red[0];
}

__global__ void k_final(const float* __restrict__ partial, float* __restrict__ out, int n) {
    __shared__ double red[256];
    const int tid = threadIdx.x;
    double a = 0.0;
    for (int i = tid; i < n; i += 256) a += (double)partial[i];
    red[tid] = a; __syncthreads();
    for (int off = 128; off > 0; off >>= 1) {
        if (tid < off) red[tid] += red[tid+off];
        __syncthreads();
    }
    if (tid == 0) out[0] = (float)(red[0] / (double)((size_t)Bb*HW));
}

extern "C" void kernel_launch(void* const* d_in, const int* in_sizes, int n_in,
                              void* d_out, int out_size, void* d_ws, size_t ws_size,
                              hipStream_t stream) {
    const float* pred = (const float*)d_in[0];   // [4,1,384,384] f32
    const float* init = (const float*)d_in[1];   // [4,64,2] f32
    float* out = (float*)d_out;
    char* ws = (char*)d_ws;
    // ws: pA @0 | pB @4096 | partial @19456 (2304 f32) | gimg @28672
    float4* pA     = (float4*)(ws);
    float4* pB     = (float4*)(ws + 4096);
    float* partial = (float*)(ws + 19456);
    float2* gimg   = (float2*)(ws + 28672);

    k_conv  <<<dim3(12,12,4),     dim3(256), 0, stream>>>(pred, gimg);
    k_snake <<<dim3(4),           dim3(256), 0, stream>>>(gimg, pred, init, pA, pB);
    k_render<<<dim3(TPB,TPB,Bb),  dim3(256), 0, stream>>>(pred, pA, pB, partial);
    k_final <<<dim3(1),           dim3(256), 0, stream>>>(partial, out, Bb*NTILES);
}

// Round 11
// 39.854 us; speedup vs baseline: 5.2716x; 1.1304x over previous
//
#include <hip/hip_runtime.h>

#define Hh 384
#define Ww 384
#define Bb 4
#define NN 64
#define HW (Hh*Ww)
#define NSEG (NN-1)
#define TPB 24                        // 24x24 tiles of 16x16
#define NTILES (TPB*TPB)              // 576 per batch

// ---------------- compile-time Ainv = (I + 0.1*A)^-1 (banded LU, f32) ------
struct AinvT { float a[NN][NN]; };
constexpr AinvT make_ainv() {
    AinvT R{};
    float d[NN] = {}, u1[NN] = {}, u2[NN] = {}, b1[NN] = {}, L1[NN] = {}, L2[NN] = {};
    for (int k = 0; k < NN-1; ++k) { d[k] += 0.01f; d[k+1] += 0.01f; u1[k] -= 0.01f; }
    for (int k = 0; k < NN-2; ++k) {
        d[k] += 0.01f; d[k+1] += 0.04f; d[k+2] += 0.01f;
        u1[k] -= 0.02f; u1[k+1] -= 0.02f; u2[k] += 0.01f;
    }
    for (int k = 0; k < NN; ++k) {
        d[k]  = 1.0f + 0.1f*d[k];
        u1[k] = 0.1f*u1[k];
        u2[k] = 0.1f*u2[k];
        b1[k] = u1[k];
    }
    for (int k = 0; k < NN; ++k) {
        float di = d[k];
        if (k+1 < NN) { float l = b1[k]/di; L1[k] = l; d[k+1] -= l*u1[k]; if (k+2 < NN) u1[k+1] -= l*u2[k]; }
        if (k+2 < NN) { float l = u2[k]/di; L2[k] = l; b1[k+1] -= l*u1[k]; d[k+2] -= l*u2[k]; }
    }
    for (int t = 0; t < NN; ++t) {
        float y[NN] = {}, x[NN] = {};
        for (int k = 0; k < NN; ++k) {
            float v = (k == t) ? 1.0f : 0.0f;
            if (k >= 1) v -= L1[k-1]*y[k-1];
            if (k >= 2) v -= L2[k-2]*y[k-2];
            y[k] = v;
        }
        for (int kk = 0; kk < NN; ++kk) {
            int k = NN-1-kk;
            float v = y[k];
            if (k+1 < NN) v -= u1[k]*x[k+1];
            if (k+2 < NN) v -= u2[k]*x[k+2];
            x[k] = v/d[k];
        }
        for (int k = 0; k < NN; ++k) R.a[k][t] = x[k];
    }
    return R;
}
__device__ constexpr AinvT g_Ainv = make_ainv();

// ---------------- conv (separable DoG) -> gimg [B][H][W][2] ----------------
#define TILE 32
#define HALO 8
__global__ __launch_bounds__(256) void k_conv(const float* __restrict__ img,
        float2* __restrict__ gimg) {
    __shared__ float sIn[TILE+2*HALO][TILE+2*HALO];      // 48x48
    __shared__ float sColG[TILE+2*HALO][TILE];
    __shared__ float sColD[TILE+2*HALO][TILE];
    __shared__ float gtap[17], dtap[17];
    const int b  = blockIdx.z;
    const int x0 = blockIdx.x * TILE;
    const int y0 = blockIdx.y * TILE;
    const int tid = threadIdx.x;
    if (tid == 0) {
        float s = 0.f;
        for (int i = 0; i < 17; ++i) {
            float xv = (float)(i - 8);
            float e  = expf(-0.5f * (xv*0.5f)*(xv*0.5f));
            gtap[i] = e; s += e;
            dtap[i] = -(xv*0.25f) * e;
        }
        for (int i = 0; i < 17; ++i) gtap[i] /= s;
    }
    const float* im = img + b*HW;
    for (int idx = tid; idx < 48*48; idx += blockDim.x) {
        int r = idx / 48, c = idx % 48;
        int gx = x0 + r - HALO, gy = y0 + c - HALO;
        float v = 0.f;
        if (gx >= 0 && gx < Hh && gy >= 0 && gy < Ww) v = im[gx*Ww + gy];
        sIn[r][c] = v;
    }
    __syncthreads();
    for (int idx = tid; idx < 48*TILE; idx += blockDim.x) {
        int r = idx / TILE, c = idx % TILE;
        float ag = 0.f, ad = 0.f;
#pragma unroll
        for (int k = 0; k < 17; ++k) {
            float v = sIn[r][c+k];
            ag += gtap[k]*v;
            ad += dtap[k]*v;
        }
        sColG[r][c] = ag; sColD[r][c] = ad;
    }
    __syncthreads();
    float2* gg = gimg + (size_t)b*HW;
    for (int idx = tid; idx < TILE*TILE; idx += blockDim.x) {
        int xo = idx / TILE, c = idx % TILE;
        float a0 = 0.f, a1 = 0.f;
#pragma unroll
        for (int k = 0; k < 17; ++k) {
            a0 += dtap[k]*sColG[xo+k][c];
            a1 += gtap[k]*sColD[xo+k][c];
        }
        int gx = x0+xo, gy = y0+c;
        gg[gx*Ww+gy] = make_float2(10.f*a0, 10.f*a1);
    }
}

// ------- snake (20 steps, const Ainv) + node-batched widths + prep ---------
__global__ __launch_bounds__(256) void k_snake(const float2* __restrict__ gimg,
                        const float* __restrict__ pred, const float* __restrict__ init,
                        float4* __restrict__ pA, float4* __restrict__ pB) {
    __shared__ float2 stxy[NN];
    __shared__ float swf[NN];
    const int b = blockIdx.x;
    const int tid = threadIdx.x;
    const int i = tid >> 2;
    const int q = tid & 3;

    float ar[16];
#pragma unroll
    for (int k = 0; k < 16; ++k) ar[k] = g_Ainv.a[i][q*16 + k];

    float px = init[(b*NN + i)*2 + 0];
    float py = init[(b*NN + i)*2 + 1];
    const float2* g = gimg + (size_t)b*HW;

    for (int s = 0; s < 20; ++s) {
        float x = fminf(fmaxf(px, 0.f), (float)(Hh-1));
        float y = fminf(fmaxf(py, 0.f), (float)(Ww-1));
        int x0i = (int)floorf(x); x0i = min(max(x0i, 0), Hh-2);
        int y0i = (int)floorf(y); y0i = min(max(y0i, 0), Ww-2);
        float fx = x - (float)x0i, fy = y - (float)y0i;
        int base = x0i*Ww + y0i;
        if (q == 0) {
            float2 v00 = g[base],    v01 = g[base+1];
            float2 v10 = g[base+Ww], v11 = g[base+Ww+1];
            float t0x = v00.x*(1.f-fy) + v01.x*fy;
            float t0y = v00.y*(1.f-fy) + v01.y*fy;
            float b0x = v10.x*(1.f-fy) + v11.x*fy;
            float b0y = v10.y*(1.f-fy) + v11.y*fy;
            float f0 = t0x*(1.f-fx) + b0x*fx;
            float f1 = t0y*(1.f-fx) + b0y*fx;
            stxy[i] = make_float2(px + 0.1f*f0, py + 0.1f*f1);
        }
        __syncthreads();
        float ax = 0.f, ay = 0.f;
#pragma unroll
        for (int k = 0; k < 16; ++k) {
            float2 tv = stxy[q*16 + k];
            ax = fmaf(ar[k], tv.x, ax);
            ay = fmaf(ar[k], tv.y, ay);
        }
        ax += __shfl_xor(ax, 1); ay += __shfl_xor(ay, 1);
        ax += __shfl_xor(ax, 2); ay += __shfl_xor(ay, 2);
        px = ax; py = ay;
        __syncthreads();
    }
    if (q == 0) stxy[i] = make_float2(px, py);
    __syncthreads();

    // ---- radial widths: node-batched radius-1 probe + rare serial tail ----
    // r=1 resolves ~99.6% of nodes, and BOTH r=1 outcomes give width 0
    // (hit -> rf-1 = 0; oob -> 0). So: issue all 16 nodes' r=1 loads at once
    // (one latency), ballot in original node order, and only unresolved
    // nodes (wave-uniform flag) run the exact serial loop from r=2.
    const float* p = pred + (size_t)b*HW;
    const int wid  = tid >> 6;
    const int lane = tid & 63;
    const bool active = lane < 36;
    const float theta = (float)(10*lane) * 0.017453292519943295f;
    const float cth = cosf(theta), sth = sinf(theta);

    float v1[16];
    unsigned inbm = 0u;
#pragma unroll
    for (int nc = 0; nc < 16; ++nc) {
        const int node = wid*16 + nc;
        const float sx = rintf(stxy[node].x);
        const float sy = rintf(stxy[node].y);
        int xi = (int)floorf(sx + cth);     // r = 1
        int yi = (int)floorf(sy + sth);
        bool inb = (xi >= 0) & (xi < Hh) & (yi >= 0) & (yi < Ww);
        inbm |= (inb ? 1u : 0u) << nc;
        int cx = min(max(xi, 0), Hh-1);
        int cy = min(max(yi, 0), Ww-1);
        v1[nc] = p[cx*Ww + cy];             // 16 independent loads in flight
    }
#pragma unroll
    for (int nc = 0; nc < 16; ++nc) {
        const int node = wid*16 + nc;
        bool inb = (inbm >> nc) & 1u;
        bool hit = active && inb && (v1[nc] > 0.f);   // sigmoid(-p)<0.5 <=> p>0
        bool oob = active && !inb;
        unsigned long long mh = __ballot(hit);
        unsigned long long mo = __ballot(oob);
        float w = 0.f;                       // r=1 resolution always => 0
        if (!(mh | mo)) {                    // wave-uniform rare path
            const float sx = rintf(stxy[node].x);
            const float sy = rintf(stxy[node].y);
            for (int r = 2; r < Hh; ++r) {
                float rf = (float)r;
                bool hit2 = false, oob2 = false;
                if (active) {
                    int xi = (int)floorf(sx + rf*cth);
                    int yi = (int)floorf(sy + rf*sth);
                    bool inb2 = (xi >= 0) & (xi < Hh) & (yi >= 0) & (yi < Ww);
                    if (!inb2) oob2 = true;
                    else if (p[xi*Ww + yi] > 0.f) hit2 = true;
                }
                unsigned long long mh2 = __ballot(hit2);
                unsigned long long mo2 = __ballot(oob2);
                if (mh2 | mo2) { w = mh2 ? (rf - 1.f) : 0.f; break; }
            }
        }
        if (lane == 0) swf[node] = w;
    }
    __syncthreads();

    // ---- segment prep ----
    if (tid < NSEG) {
        float2 P0 = stxy[tid], P1 = stxy[tid+1];
        float vx = P1.x - P0.x, vy = P1.y - P0.y;
        float vv = vx*vx + vy*vy + 1e-8f;
        float w0 = swf[tid], w1 = swf[tid+1];
        pA[b*NSEG + tid] = make_float4(P0.x, P0.y, vx, vy);
        pB[b*NSEG + tid] = make_float4(1.0f/vv, w0, w1 - w0, 0.f);
    }
}

// ------- render: 16x16 tiles, LDS-staged params, per-tile segment culling --
__global__ __launch_bounds__(256) void k_render(const float* __restrict__ pred,
                        const float4* __restrict__ pAg, const float4* __restrict__ pBg,
                        float* __restrict__ partial) {
    __shared__ float4 sSa[NSEG], sSb[NSEG];
    __shared__ int slist[NSEG];
    __shared__ int scount;
    __shared__ float red[256];
    const int b   = blockIdx.z;
    const int tid = threadIdx.x;
    const int row0 = blockIdx.x * 16, col0 = blockIdx.y * 16;
    if (tid == 0) scount = 0;
    if (tid < NSEG) {
        sSa[tid] = pAg[b*NSEG + tid];
        sSb[tid] = pBg[b*NSEG + tid];
    }
    __syncthreads();
    if (tid < NSEG) {
        const float4 A = sSa[tid];
        const float4 Bv = sSb[tid];
        float cx = (float)row0 + 7.5f, cy = (float)col0 + 7.5f;
        float dx = cx - A.x, dy = cy - A.y;
        float t = fmaf(dy, A.w, dx*A.z) * Bv.x;
        t = fminf(fmaxf(t, 0.f), 1.f);
        float ex = fmaf(-t, A.z, dx);
        float ey = fmaf(-t, A.w, dy);
        float dc = sqrtf(ex*ex + ey*ey);
        float wmax = fmaxf(Bv.y, Bv.y + Bv.z);
        float lim = fmaxf(15.0f, wmax) + 10.6066f + 0.05f;
        if (dc <= lim) {
            int idx = atomicAdd(&scount, 1);
            slist[idx] = tid;
        }
    }
    __syncthreads();
    const int cnt = scount;
    const int r = tid >> 4, c = tid & 15;
    const float fx = (float)(row0 + r), fy = (float)(col0 + c);
    float m1 = 1e30f, m2 = 1e30f;
    for (int k = 0; k < cnt; ++k) {
        const int s2 = slist[k];
        const float4 A = sSa[s2];
        const float4 Bv = sSb[s2];
        float dx = fx - A.x, dy = fy - A.y;
        float t = fmaf(dy, A.w, dx*A.z) * Bv.x;
        t = fminf(fmaxf(t, 0.f), 1.f);
        float ex = fmaf(-t, A.z, dx);
        float ey = fmaf(-t, A.w, dy);
        float d2 = fmaf(ex, ex, fmaf(ey, ey, 1e-12f));
        float wt = fmaf(t, Bv.z, Bv.y);
        m1 = fminf(m1, d2);
        m2 = fminf(m2, fmaf(-wt, wt, d2));
    }
    float dmap = fminf(sqrtf(m1), 15.f);
    float pm = (m2 <= 0.f) ? 1.f : 0.f;
    float pv = pred[(size_t)b*HW + (row0 + r)*Ww + (col0 + c)];
    float sg = 1.f/(1.f + expf(-pv));
    float t1 = pv - dmap, t2 = sg - pm;
    red[tid] = t1*t1 + t2*t2;
    __syncthreads();
    for (int off = 128; off > 0; off >>= 1) {
        if (tid < off) red[tid] += red[tid+off];
        __syncthreads();
    }
    if (tid == 0)
        partial[b*NTILES + blockIdx.y*TPB + blockIdx.x] = red[0];
}

__global__ void k_final(const float* __restrict__ partial, float* __restrict__ out, int n) {
    __shared__ double red[256];
    const int tid = threadIdx.x;
    double a = 0.0;
    for (int i = tid; i < n; i += 256) a += (double)partial[i];
    red[tid] = a; __syncthreads();
    for (int off = 128; off > 0; off >>= 1) {
        if (tid < off) red[tid] += red[tid+off];
        __syncthreads();
    }
    if (tid == 0) out[0] = (float)(red[0] / (double)((size_t)Bb*HW));
}

extern "C" void kernel_launch(void* const* d_in, const int* in_sizes, int n_in,
                              void* d_out, int out_size, void* d_ws, size_t ws_size,
                              hipStream_t stream) {
    const float* pred = (const float*)d_in[0];   // [4,1,384,384] f32
    const float* init = (const float*)d_in[1];   // [4,64,2] f32
    float* out = (float*)d_out;
    char* ws = (char*)d_ws;
    // ws: pA @0 | pB @4096 | partial @19456 (2304 f32) | gimg @28672
    float4* pA     = (float4*)(ws);
    float4* pB     = (float4*)(ws + 4096);
    float* partial = (float*)(ws + 19456);
    float2* gimg   = (float2*)(ws + 28672);

    k_conv  <<<dim3(12,12,4),     dim3(256), 0, stream>>>(pred, gimg);
    k_snake <<<dim3(4),           dim3(256), 0, stream>>>(gimg, pred, init, pA, pB);
    k_render<<<dim3(TPB,TPB,Bb),  dim3(256), 0, stream>>>(pred, pA, pB, partial);
    k_final <<<dim3(1),           dim3(256), 0, stream>>>(partial, out, Bb*NTILES);
}